// Round 4
// baseline (122.498 us; speedup 1.0000x reference)
//
#include <hip/hip_runtime.h>

// Problem dims
#define B_    2
#define NCAM_ 6
#define J_    23
#define HM_   160
#define W_    640
#define H_    512
#define D_    50

static constexpr long long HF_SIZE = (long long)B_ * J_ * D_ * D_ * D_;        // 5,750,000
static constexpr long long HP_SIZE = (long long)B_ * NCAM_ * J_ * H_ * W_;     // 90,439,680
static constexpr int NBJ = B_ * J_;                                            // 46
static constexpr int CHUNKS = 32;
static constexpr int SP_BLOCKS = NBJ * CHUNKS;                                 // 1472
static constexpr int NPLANES = B_ * NCAM_ * J_;                                // 276
static constexpr int PLANE_F4 = (H_ * W_) / 4;                                 // 81,920
static constexpr int PAD_CHUNKS = 16;                                          // blocks per plane
static constexpr int PAD_BLOCKS = NPLANES * PAD_CHUNKS;                        // 4416
static constexpr int CHUNK_F4 = PLANE_F4 / PAD_CHUNKS;                         // 5120

// ---------------------------------------------------------------------------
// Kernel 1: blocks [0,SP_BLOCKS)               -> softplus + reduce partials
//           blocks [SP_BLOCKS,SP_BLOCKS+PAD_BLOCKS) -> write-once padded canvas
// Every canvas float4 is written exactly once (16B-aligned stores). Crop data
// is gathered with branchless per-field dword loads (28 MB, coalesced).
// ---------------------------------------------------------------------------
__global__ void fused_main(const float4* __restrict__ vol4,
                           float4* __restrict__ out_hf4,
                           float* __restrict__ partials,
                           const float* __restrict__ hm,
                           const int* __restrict__ centerHM,
                           float4* __restrict__ out_pad4) {
    const int gid = blockIdx.x;
    if (gid < SP_BLOCKS) {
        // ---- softplus + 4-way reduction ----
        const int NE4 = (D_ * D_ * D_) / 4;              // 31,250
        const int bj = gid / CHUNKS;
        const int chunk = gid % CHUNKS;
        const long long base4 = (long long)bj * NE4;

        float s = 0.f, sx = 0.f, sy = 0.f, sz = 0.f;
        for (int i = chunk * blockDim.x + threadIdx.x; i < NE4; i += CHUNKS * blockDim.x) {
            const float4 v = vol4[base4 + i];
            float4 sp;
            sp.x = fmaxf(v.x, 0.f) + log1pf(__expf(-fabsf(v.x)));
            sp.y = fmaxf(v.y, 0.f) + log1pf(__expf(-fabsf(v.y)));
            sp.z = fmaxf(v.z, 0.f) + log1pf(__expf(-fabsf(v.z)));
            sp.w = fmaxf(v.w, 0.f) + log1pf(__expf(-fabsf(v.w)));
            out_hf4[base4 + i] = sp;
            const int e0 = i * 4;
            const int zz = e0 % D_;                      // e0..e0+3 share the
            const int t  = e0 / D_;                      // same row (50 | 4? no,
            const int yy = t % D_;                       // but D=50, e0%50<=46
            const int xx = t / D_;                       // since e0%2==0... )
            // careful: 50 % 4 != 0, so zz may wrap within a float4.
            // handle exactly:
            float zzf0 = (float)zz;
            float s4 = sp.x + sp.y + sp.z + sp.w;
            if (zz <= D_ - 4) {
                // all four share (xx,yy), zz..zz+3 contiguous
                s  += s4;
                sx += s4 * (float)xx;
                sy += s4 * (float)yy;
                sz += sp.x * zzf0 + sp.y * (zzf0 + 1.f) + sp.z * (zzf0 + 2.f) + sp.w * (zzf0 + 3.f);
            } else {
                const float* spp = &sp.x;
                #pragma unroll
                for (int k = 0; k < 4; ++k) {
                    const int e  = e0 + k;
                    const int z2 = e % D_;
                    const int t2 = e / D_;
                    const int y2 = t2 % D_;
                    const int x2 = t2 / D_;
                    const float p = spp[k];
                    s  += p;
                    sx += p * (float)x2;
                    sy += p * (float)y2;
                    sz += p * (float)z2;
                }
            }
        }

        #pragma unroll
        for (int off = 32; off > 0; off >>= 1) {
            s  += __shfl_down(s,  off, 64);
            sx += __shfl_down(sx, off, 64);
            sy += __shfl_down(sy, off, 64);
            sz += __shfl_down(sz, off, 64);
        }
        __shared__ float sm[4][4];
        const int lane = threadIdx.x & 63;
        const int wid  = threadIdx.x >> 6;
        if (lane == 0) {
            sm[0][wid] = s; sm[1][wid] = sx; sm[2][wid] = sy; sm[3][wid] = sz;
        }
        __syncthreads();
        if (threadIdx.x == 0) {
            float a0 = 0.f, a1 = 0.f, a2 = 0.f, a3 = 0.f;
            #pragma unroll
            for (int w = 0; w < 4; ++w) {
                a0 += sm[0][w]; a1 += sm[1][w]; a2 += sm[2][w]; a3 += sm[3][w];
            }
            partials[gid * 4 + 0] = a0;
            partials[gid * 4 + 1] = a1;
            partials[gid * 4 + 2] = a2;
            partials[gid * 4 + 3] = a3;
        }
    } else {
        // ---- write-once padded canvas ----
        const int pb    = gid - SP_BLOCKS;
        const int plane = pb >> 4;                       // /PAD_CHUNKS
        const int chunk = pb & (PAD_CHUNKS - 1);
        const int bcam  = plane / J_;                    // magic-mul, uniform

        const int cx = centerHM[bcam * 2 + 0];
        const int cy = centerHM[bcam * 2 + 1];
        int x0 = cx / 2 - HM_ / 2;
        int y0 = cy / 2 - HM_ / 2;
        x0 = min(max(x0, 0), W_ - HM_);
        y0 = min(max(y0, 0), H_ - HM_);

        const float* __restrict__ src = hm + (long long)plane * (HM_ * HM_);
        float4* __restrict__ outp = out_pad4 + (long long)plane * PLANE_F4;

        const int fbase = chunk * CHUNK_F4;
        #pragma unroll 4
        for (int it = 0; it < CHUNK_F4; it += 256) {
            const int f  = fbase + it + threadIdx.x;
            const int y  = f / (W_ / 4);                 // u32 magic-mul
            const int xf = (f - y * (W_ / 4)) << 2;
            const int dy = y - y0;
            const int dxb = xf - x0;
            float4 v = make_float4(0.f, 0.f, 0.f, 0.f);
            if ((unsigned)dy < (unsigned)HM_) {
                const float* __restrict__ row = src + dy * HM_;
                if ((unsigned)(dxb + 0) < (unsigned)HM_) v.x = row[dxb + 0];
                if ((unsigned)(dxb + 1) < (unsigned)HM_) v.y = row[dxb + 1];
                if ((unsigned)(dxb + 2) < (unsigned)HM_) v.z = row[dxb + 2];
                if ((unsigned)(dxb + 3) < (unsigned)HM_) v.w = row[dxb + 3];
            }
            outp[f] = v;
        }
    }
}

// ---------------------------------------------------------------------------
// Kernel 2: tiny finalize (1 block)
// ---------------------------------------------------------------------------
__global__ void finalize_points(const float* __restrict__ partials,
                                const float* __restrict__ c3d,
                                float* __restrict__ out_p3d) {
    const int bj = threadIdx.x;
    if (bj < NBJ) {
        const int b = bj / J_;
        float a0 = 0.f, a1 = 0.f, a2 = 0.f, a3 = 0.f;
        for (int c = 0; c < CHUNKS; ++c) {
            const float* p = &partials[(bj * CHUNKS + c) * 4];
            a0 += p[0]; a1 += p[1]; a2 += p[2]; a3 += p[3];
        }
        const float inv = 1.0f / a0;
        out_p3d[bj * 3 + 0] = a1 * inv * 4.0f - 100.0f + c3d[b * 3 + 0];
        out_p3d[bj * 3 + 1] = a2 * inv * 4.0f - 100.0f + c3d[b * 3 + 1];
        out_p3d[bj * 3 + 2] = a3 * inv * 4.0f - 100.0f + c3d[b * 3 + 2];
    }
}

extern "C" void kernel_launch(void* const* d_in, const int* in_sizes, int n_in,
                              void* d_out, int out_size, void* d_ws, size_t ws_size,
                              hipStream_t stream) {
    const float* hm_batch  = (const float*)d_in[0];   // [B,NCAM,J,HM,HM]
    const float* vol       = (const float*)d_in[1];   // [B,J,D,D,D]
    const float* c3d       = (const float*)d_in[2];   // [B,1,3]
    const int*   centerHM  = (const int*)d_in[3];     // [B,NCAM,2]

    float* out     = (float*)d_out;
    float* out_hf  = out;                              // heatmap_final
    float* out_pad = out + HF_SIZE;                    // heatmaps_padded
    float* out_p3d = out + HF_SIZE + HP_SIZE;          // points3D

    float* partials = (float*)d_ws;                    // [SP_BLOCKS*4]

    fused_main<<<SP_BLOCKS + PAD_BLOCKS, 256, 0, stream>>>(
        (const float4*)vol, (float4*)out_hf, partials,
        hm_batch, centerHM, (float4*)out_pad);

    finalize_points<<<1, 64, 0, stream>>>(partials, c3d, out_p3d);
}

// Round 5
// 102.742 us; speedup vs baseline: 1.1923x; 1.1923x over previous
//
#include <hip/hip_runtime.h>

// Problem dims
#define B_    2
#define NCAM_ 6
#define J_    23
#define HM_   160
#define W_    640
#define H_    512
#define D_    50

static constexpr long long HF_SIZE = (long long)B_ * J_ * D_ * D_ * D_;        // 5,750,000
static constexpr long long HP_SIZE = (long long)B_ * NCAM_ * J_ * H_ * W_;     // 90,439,680
static constexpr int NBJ = B_ * J_;                                            // 46
static constexpr int CHUNKS = 32;
static constexpr int SP_BLOCKS = NBJ * CHUNKS;                                 // 1472
static constexpr int NPLANES = B_ * NCAM_ * J_;                                // 276
static constexpr int W4 = W_ / 4;                                              // 160 f4 per row
static constexpr int PLANE_F4 = H_ * W4;                                       // 81,920
static constexpr int INT_F4 = HM_ * W4;                                        // 25,600 (crop band)
static constexpr int EXT_F4 = PLANE_F4 - INT_F4;                               // 56,320
static constexpr int EXTB_PER_PLANE = 16;                                      // 3,520 f4/block
static constexpr int INTB_PER_PLANE = 8;                                       // 3,200 f4/block
static constexpr int EXT_BLOCKS = NPLANES * EXTB_PER_PLANE;                    // 4416
static constexpr int INT_BLOCKS = NPLANES * INTB_PER_PLANE;                    // 2208
static constexpr int TOTAL_BLOCKS = SP_BLOCKS + EXT_BLOCKS + INT_BLOCKS;       // 8096

// ---------------------------------------------------------------------------
// One fused kernel, three block roles:
//  [0, SP_BLOCKS)            softplus + 4-way reduction -> partials
//  [SP_BLOCKS, +EXT_BLOCKS)  zero the exterior rows (two contiguous spans,
//                            pure aligned float4 stores, no div/loads)
//  [.., +INT_BLOCKS)         write interior (crop-band) rows once: clamped
//                            gather + cndmask, aligned float4 stores
// ---------------------------------------------------------------------------
__global__ void fused_all(const float4* __restrict__ vol4,
                          float4* __restrict__ out_hf4,
                          float* __restrict__ partials,
                          const float* __restrict__ hm,
                          const int* __restrict__ centerHM,
                          float4* __restrict__ out_pad4) {
    const int gid = blockIdx.x;

    if (gid < SP_BLOCKS) {
        // ---- softplus + reduction (pair-wise exact index math) ----
        const int NE4 = (D_ * D_ * D_) / 4;              // 31,250
        const int bj = gid / CHUNKS;
        const int chunk = gid % CHUNKS;
        const long long base4 = (long long)bj * NE4;

        float s = 0.f, sx = 0.f, sy = 0.f, sz = 0.f;
        for (int i = chunk * blockDim.x + threadIdx.x; i < NE4; i += CHUNKS * blockDim.x) {
            const float4 v = vol4[base4 + i];
            float4 sp;
            sp.x = fmaxf(v.x, 0.f) + log1pf(__expf(-fabsf(v.x)));
            sp.y = fmaxf(v.y, 0.f) + log1pf(__expf(-fabsf(v.y)));
            sp.z = fmaxf(v.z, 0.f) + log1pf(__expf(-fabsf(v.z)));
            sp.w = fmaxf(v.w, 0.f) + log1pf(__expf(-fabsf(v.w)));
            out_hf4[base4 + i] = sp;
            // e0 = 4i is even -> z0 even <= 48, pair (z0, z0+1) never wraps.
            const int e0 = i * 4;
            const int t0 = e0 / D_;       const int z0 = e0 - t0 * D_;
            const int x0i = t0 / D_;      const int y0i = t0 - x0i * D_;
            const int e2 = e0 + 2;
            const int t2 = e2 / D_;       const int z2 = e2 - t2 * D_;
            const int x2i = t2 / D_;      const int y2i = t2 - x2i * D_;
            const float p01 = sp.x + sp.y;
            const float p23 = sp.z + sp.w;
            s  += p01 + p23;
            sx += p01 * (float)x0i + p23 * (float)x2i;
            sy += p01 * (float)y0i + p23 * (float)y2i;
            sz += sp.x * (float)z0 + sp.y * (float)(z0 + 1)
                + sp.z * (float)z2 + sp.w * (float)(z2 + 1);
        }

        #pragma unroll
        for (int off = 32; off > 0; off >>= 1) {
            s  += __shfl_down(s,  off, 64);
            sx += __shfl_down(sx, off, 64);
            sy += __shfl_down(sy, off, 64);
            sz += __shfl_down(sz, off, 64);
        }
        __shared__ float sm[4][4];
        const int lane = threadIdx.x & 63;
        const int wid  = threadIdx.x >> 6;
        if (lane == 0) {
            sm[0][wid] = s; sm[1][wid] = sx; sm[2][wid] = sy; sm[3][wid] = sz;
        }
        __syncthreads();
        if (threadIdx.x == 0) {
            float a0 = 0.f, a1 = 0.f, a2 = 0.f, a3 = 0.f;
            #pragma unroll
            for (int w = 0; w < 4; ++w) {
                a0 += sm[0][w]; a1 += sm[1][w]; a2 += sm[2][w]; a3 += sm[3][w];
            }
            partials[gid * 4 + 0] = a0;
            partials[gid * 4 + 1] = a1;
            partials[gid * 4 + 2] = a2;
            partials[gid * 4 + 3] = a3;
        }
        return;
    }

    if (gid < SP_BLOCKS + EXT_BLOCKS) {
        // ---- exterior zero rows: two contiguous spans, pure stores ----
        const int pb    = gid - SP_BLOCKS;
        const int plane = pb >> 4;                       // / EXTB_PER_PLANE
        const int sub   = pb & (EXTB_PER_PLANE - 1);
        const int bcam  = plane / J_;                    // uniform (scalar)

        const int cy = centerHM[bcam * 2 + 1];
        int y0 = cy / 2 - HM_ / 2;
        y0 = min(max(y0, 0), H_ - HM_);
        const int top = y0 * W4;                         // f4 before crop band

        float4* __restrict__ outp = out_pad4 + (long long)plane * PLANE_F4;
        const float4 z = make_float4(0.f, 0.f, 0.f, 0.f);
        const int e_end = min((sub + 1) * (EXT_F4 / EXTB_PER_PLANE), EXT_F4);
        for (int e = sub * (EXT_F4 / EXTB_PER_PLANE) + threadIdx.x; e < e_end; e += 256) {
            const int dst = e < top ? e : e + INT_F4;    // skip the crop band
            outp[dst] = z;
        }
        return;
    }

    // ---- interior (crop band) rows: write-once with clamped gather ----
    {
        const int pb    = gid - SP_BLOCKS - EXT_BLOCKS;
        const int plane = pb >> 3;                       // / INTB_PER_PLANE
        const int sub   = pb & (INTB_PER_PLANE - 1);
        const int bcam  = plane / J_;                    // uniform (scalar)

        const int cx = centerHM[bcam * 2 + 0];
        const int cy = centerHM[bcam * 2 + 1];
        int x0 = cx / 2 - HM_ / 2;
        int y0 = cy / 2 - HM_ / 2;
        x0 = min(max(x0, 0), W_ - HM_);
        y0 = min(max(y0, 0), H_ - HM_);

        const float* __restrict__ src = hm + (long long)plane * (HM_ * HM_);
        float4* __restrict__ outp = out_pad4 + (long long)plane * PLANE_F4 + y0 * W4;

        const int i_end = min((sub + 1) * (INT_F4 / INTB_PER_PLANE), INT_F4);
        for (int i = sub * (INT_F4 / INTB_PER_PLANE) + threadIdx.x; i < i_end; i += 256) {
            const int dy = i / W4;                       // u32 magic-mul
            const int f  = i - dy * W4;
            const int dxb = (f << 2) - x0;
            const float* __restrict__ row = src + dy * HM_;
            float4 v;
            // clamped unconditional loads + select (no exec-mask branches)
            #pragma unroll
            for (int k = 0; k < 4; ++k) {
                const int dx = dxb + k;
                const int dxc = min(max(dx, 0), HM_ - 1);
                const float val = row[dxc];
                (&v.x)[k] = ((unsigned)dx < (unsigned)HM_) ? val : 0.f;
            }
            outp[i] = v;
        }
    }
}

// ---------------------------------------------------------------------------
// Tiny finalize (1 block)
// ---------------------------------------------------------------------------
__global__ void finalize_points(const float* __restrict__ partials,
                                const float* __restrict__ c3d,
                                float* __restrict__ out_p3d) {
    const int bj = threadIdx.x;
    if (bj < NBJ) {
        const int b = bj / J_;
        float a0 = 0.f, a1 = 0.f, a2 = 0.f, a3 = 0.f;
        for (int c = 0; c < CHUNKS; ++c) {
            const float* p = &partials[(bj * CHUNKS + c) * 4];
            a0 += p[0]; a1 += p[1]; a2 += p[2]; a3 += p[3];
        }
        const float inv = 1.0f / a0;
        out_p3d[bj * 3 + 0] = a1 * inv * 4.0f - 100.0f + c3d[b * 3 + 0];
        out_p3d[bj * 3 + 1] = a2 * inv * 4.0f - 100.0f + c3d[b * 3 + 1];
        out_p3d[bj * 3 + 2] = a3 * inv * 4.0f - 100.0f + c3d[b * 3 + 2];
    }
}

extern "C" void kernel_launch(void* const* d_in, const int* in_sizes, int n_in,
                              void* d_out, int out_size, void* d_ws, size_t ws_size,
                              hipStream_t stream) {
    const float* hm_batch  = (const float*)d_in[0];   // [B,NCAM,J,HM,HM]
    const float* vol       = (const float*)d_in[1];   // [B,J,D,D,D]
    const float* c3d       = (const float*)d_in[2];   // [B,1,3]
    const int*   centerHM  = (const int*)d_in[3];     // [B,NCAM,2]

    float* out     = (float*)d_out;
    float* out_hf  = out;                              // heatmap_final
    float* out_pad = out + HF_SIZE;                    // heatmaps_padded (16B-aligned: HF_SIZE%4==0)
    float* out_p3d = out + HF_SIZE + HP_SIZE;          // points3D

    float* partials = (float*)d_ws;                    // [SP_BLOCKS*4]

    fused_all<<<TOTAL_BLOCKS, 256, 0, stream>>>(
        (const float4*)vol, (float4*)out_hf, partials,
        hm_batch, centerHM, (float4*)out_pad);

    finalize_points<<<1, 64, 0, stream>>>(partials, c3d, out_p3d);
}

// Round 6
// 96.709 us; speedup vs baseline: 1.2667x; 1.0624x over previous
//
#include <hip/hip_runtime.h>

// Problem dims
#define B_    2
#define NCAM_ 6
#define J_    23
#define HM_   160
#define W_    640
#define H_    512
#define D_    50

static constexpr long long HF_SIZE = (long long)B_ * J_ * D_ * D_ * D_;        // 5,750,000
static constexpr long long HP_SIZE = (long long)B_ * NCAM_ * J_ * H_ * W_;     // 90,439,680
static constexpr int NBJ = B_ * J_;                                            // 46
static constexpr int CHUNKS = 32;
static constexpr int SP_BLOCKS = NBJ * CHUNKS;                                 // 1472
static constexpr int NPLANES = B_ * NCAM_ * J_;                                // 276
static constexpr int W4 = W_ / 4;                                              // 160 f4 per canvas row
static constexpr int HM4 = HM_ / 4;                                            // 40 f4 per crop row
static constexpr int PLANE_F4 = H_ * W4;                                       // 81,920
static constexpr int INT_F4 = HM_ * W4;                                        // 25,600 (crop band)
static constexpr int EXT_F4 = PLANE_F4 - INT_F4;                               // 56,320
static constexpr int EXTB_PER_PLANE = 16;                                      // 3,520 f4/block
static constexpr int EXT_BLOCKS = NPLANES * EXTB_PER_PLANE;                    // 4416
static constexpr int INT_ROWS = NPLANES * HM_;                                 // 44,160 crop rows
static constexpr int ROWS_PER_WAVE = 16;
static constexpr int INT_BLOCKS = INT_ROWS / (4 * ROWS_PER_WAVE);              // 690
static constexpr int TOTAL_BLOCKS = INT_BLOCKS + SP_BLOCKS + EXT_BLOCKS;       // 6578

// ---------------------------------------------------------------------------
// One fused kernel, three roles (write-once canvas, all stores 16B-aligned,
// all global loads fully packed):
//  [0, INT_BLOCKS)        crop-band rows: aligned f4 row load -> shfl_up lane
//                         rotation (uniform r = x0&3) -> aligned f4 stores;
//                         non-crop columns of the row get pure zero stores.
//  [+, SP_BLOCKS)         softplus + 4-way reduction -> partials
//  [+, EXT_BLOCKS)        exterior rows: two contiguous spans of pure zero
//                         f4 stores (fillBuffer-shaped loop)
// ---------------------------------------------------------------------------
__global__ void fused_all(const float4* __restrict__ vol4,
                          float4* __restrict__ out_hf4,
                          float* __restrict__ partials,
                          const float4* __restrict__ hm4,
                          const int* __restrict__ centerHM,
                          float4* __restrict__ out_pad4) {
    const int gid = blockIdx.x;

    if (gid < INT_BLOCKS) {
        // ---- crop-band rows via uniform lane rotation ----
        const int wgl  = gid * 4 + (threadIdx.x >> 6);   // global wave id
        const int lane = threadIdx.x & 63;
        const float4 z = make_float4(0.f, 0.f, 0.f, 0.f);

        for (int rr = 0; rr < ROWS_PER_WAVE; ++rr) {
            const int row   = wgl * ROWS_PER_WAVE + rr;  // < 44,160 exactly
            const int plane = row / HM_;                 // u32 magic-mul
            const int dy    = row - plane * HM_;
            const int bcam  = plane / J_;                // wave-uniform

            const int cx = centerHM[bcam * 2 + 0];
            const int cy = centerHM[bcam * 2 + 1];
            int x0 = min(max(cx / 2 - HM_ / 2, 0), W_ - HM_);
            int y0 = min(max(cy / 2 - HM_ / 2, 0), H_ - HM_);
            const int q = x0 >> 2;
            const int r = x0 & 3;
            const int nspan = r ? (HM4 + 1) : HM4;       // 41 or 40

            const float4* __restrict__ src4 =
                hm4 + (long long)plane * (HM_ * HM4) + dy * HM4;
            float4* __restrict__ outrow =
                out_pad4 + (long long)plane * PLANE_F4 + (y0 + dy) * W4;

            float4 s = z;
            if (lane < HM4) s = src4[lane];              // packed aligned load
            float px = __shfl_up(s.x, 1, 64);
            float py = __shfl_up(s.y, 1, 64);
            float pz = __shfl_up(s.z, 1, 64);
            float pw = __shfl_up(s.w, 1, 64);
            if (lane == 0) { px = py = pz = pw = 0.f; }

            float4 v;
            switch (r) {                                 // wave-uniform branch
                case 0:  v = s; break;
                case 1:  v = make_float4(pw, s.x, s.y, s.z); break;
                case 2:  v = make_float4(pz, pw, s.x, s.y); break;
                default: v = make_float4(py, pz, pw, s.x); break;
            }
            if (lane < nspan) outrow[q + lane] = v;      // aligned packed store

            // zero the complement columns of this row (write-once)
            const int cnt = W4 - nspan;                  // 119 or 120
            const int z0i = lane;
            if (z0i < cnt) outrow[z0i < q ? z0i : z0i + nspan] = z;
            const int z1i = lane + 64;
            if (z1i < cnt) outrow[z1i < q ? z1i : z1i + nspan] = z;
        }
        return;
    }

    if (gid < INT_BLOCKS + SP_BLOCKS) {
        // ---- softplus + reduction (pair-wise exact index math) ----
        const int sg = gid - INT_BLOCKS;
        const int NE4 = (D_ * D_ * D_) / 4;              // 31,250
        const int bj = sg / CHUNKS;
        const int chunk = sg % CHUNKS;
        const long long base4 = (long long)bj * NE4;

        float s = 0.f, sx = 0.f, sy = 0.f, sz = 0.f;
        for (int i = chunk * blockDim.x + threadIdx.x; i < NE4; i += CHUNKS * blockDim.x) {
            const float4 v = vol4[base4 + i];
            float4 sp;
            sp.x = fmaxf(v.x, 0.f) + log1pf(__expf(-fabsf(v.x)));
            sp.y = fmaxf(v.y, 0.f) + log1pf(__expf(-fabsf(v.y)));
            sp.z = fmaxf(v.z, 0.f) + log1pf(__expf(-fabsf(v.z)));
            sp.w = fmaxf(v.w, 0.f) + log1pf(__expf(-fabsf(v.w)));
            out_hf4[base4 + i] = sp;
            // e0 = 4i is even -> z0 even <= 48, pair (z0, z0+1) never wraps.
            const int e0 = i * 4;
            const int t0 = e0 / D_;       const int z0 = e0 - t0 * D_;
            const int x0i = t0 / D_;      const int y0i = t0 - x0i * D_;
            const int e2 = e0 + 2;
            const int t2 = e2 / D_;       const int z2 = e2 - t2 * D_;
            const int x2i = t2 / D_;      const int y2i = t2 - x2i * D_;
            const float p01 = sp.x + sp.y;
            const float p23 = sp.z + sp.w;
            s  += p01 + p23;
            sx += p01 * (float)x0i + p23 * (float)x2i;
            sy += p01 * (float)y0i + p23 * (float)y2i;
            sz += sp.x * (float)z0 + sp.y * (float)(z0 + 1)
                + sp.z * (float)z2 + sp.w * (float)(z2 + 1);
        }

        #pragma unroll
        for (int off = 32; off > 0; off >>= 1) {
            s  += __shfl_down(s,  off, 64);
            sx += __shfl_down(sx, off, 64);
            sy += __shfl_down(sy, off, 64);
            sz += __shfl_down(sz, off, 64);
        }
        __shared__ float sm[4][4];
        const int lane = threadIdx.x & 63;
        const int wid  = threadIdx.x >> 6;
        if (lane == 0) {
            sm[0][wid] = s; sm[1][wid] = sx; sm[2][wid] = sy; sm[3][wid] = sz;
        }
        __syncthreads();
        if (threadIdx.x == 0) {
            float a0 = 0.f, a1 = 0.f, a2 = 0.f, a3 = 0.f;
            #pragma unroll
            for (int w = 0; w < 4; ++w) {
                a0 += sm[0][w]; a1 += sm[1][w]; a2 += sm[2][w]; a3 += sm[3][w];
            }
            partials[sg * 4 + 0] = a0;
            partials[sg * 4 + 1] = a1;
            partials[sg * 4 + 2] = a2;
            partials[sg * 4 + 3] = a3;
        }
        return;
    }

    // ---- exterior zero rows: two contiguous spans, pure stores ----
    {
        const int pb    = gid - INT_BLOCKS - SP_BLOCKS;
        const int plane = pb >> 4;                       // / EXTB_PER_PLANE
        const int sub   = pb & (EXTB_PER_PLANE - 1);
        const int bcam  = plane / J_;                    // uniform (scalar)

        const int cy = centerHM[bcam * 2 + 1];
        int y0 = min(max(cy / 2 - HM_ / 2, 0), H_ - HM_);
        const int top = y0 * W4;                         // f4 before crop band

        float4* __restrict__ outp = out_pad4 + (long long)plane * PLANE_F4;
        const float4 z = make_float4(0.f, 0.f, 0.f, 0.f);
        const int e_end = (sub + 1) * (EXT_F4 / EXTB_PER_PLANE);
        for (int e = sub * (EXT_F4 / EXTB_PER_PLANE) + threadIdx.x; e < e_end; e += 256) {
            const int dst = e < top ? e : e + INT_F4;    // skip the crop band
            outp[dst] = z;
        }
    }
}

// ---------------------------------------------------------------------------
// Tiny finalize (1 block)
// ---------------------------------------------------------------------------
__global__ void finalize_points(const float* __restrict__ partials,
                                const float* __restrict__ c3d,
                                float* __restrict__ out_p3d) {
    const int bj = threadIdx.x;
    if (bj < NBJ) {
        const int b = bj / J_;
        float a0 = 0.f, a1 = 0.f, a2 = 0.f, a3 = 0.f;
        for (int c = 0; c < CHUNKS; ++c) {
            const float* p = &partials[(bj * CHUNKS + c) * 4];
            a0 += p[0]; a1 += p[1]; a2 += p[2]; a3 += p[3];
        }
        const float inv = 1.0f / a0;
        out_p3d[bj * 3 + 0] = a1 * inv * 4.0f - 100.0f + c3d[b * 3 + 0];
        out_p3d[bj * 3 + 1] = a2 * inv * 4.0f - 100.0f + c3d[b * 3 + 1];
        out_p3d[bj * 3 + 2] = a3 * inv * 4.0f - 100.0f + c3d[b * 3 + 2];
    }
}

extern "C" void kernel_launch(void* const* d_in, const int* in_sizes, int n_in,
                              void* d_out, int out_size, void* d_ws, size_t ws_size,
                              hipStream_t stream) {
    const float* hm_batch  = (const float*)d_in[0];   // [B,NCAM,J,HM,HM]
    const float* vol       = (const float*)d_in[1];   // [B,J,D,D,D]
    const float* c3d       = (const float*)d_in[2];   // [B,1,3]
    const int*   centerHM  = (const int*)d_in[3];     // [B,NCAM,2]

    float* out     = (float*)d_out;
    float* out_hf  = out;                              // heatmap_final
    float* out_pad = out + HF_SIZE;                    // heatmaps_padded (16B-aligned)
    float* out_p3d = out + HF_SIZE + HP_SIZE;          // points3D

    float* partials = (float*)d_ws;                    // [SP_BLOCKS*4]

    fused_all<<<TOTAL_BLOCKS, 256, 0, stream>>>(
        (const float4*)vol, (float4*)out_hf, partials,
        (const float4*)hm_batch, centerHM, (float4*)out_pad);

    finalize_points<<<1, 64, 0, stream>>>(partials, c3d, out_p3d);
}

// Round 7
// 93.839 us; speedup vs baseline: 1.3054x; 1.0306x over previous
//
#include <hip/hip_runtime.h>

// Problem dims
#define B_    2
#define NCAM_ 6
#define J_    23
#define HM_   160
#define W_    640
#define H_    512
#define D_    50

static constexpr long long HF_SIZE = (long long)B_ * J_ * D_ * D_ * D_;        // 5,750,000
static constexpr long long HP_SIZE = (long long)B_ * NCAM_ * J_ * H_ * W_;     // 90,439,680
static constexpr int NBJ = B_ * J_;                                            // 46
static constexpr int CHUNKS = 32;
static constexpr int SP_BLOCKS = NBJ * CHUNKS;                                 // 1472
static constexpr int NPLANES = B_ * NCAM_ * J_;                                // 276
static constexpr int W4 = W_ / 4;                                              // 160 f4 per canvas row
static constexpr int HM4 = HM_ / 4;                                            // 40 f4 per crop row
static constexpr int PLANE_F4 = H_ * W4;                                       // 81,920
static constexpr int INT_F4 = HM_ * W4;                                        // 25,600 (crop band)
static constexpr int EXT_F4 = PLANE_F4 - INT_F4;                               // 56,320
static constexpr int EXTB_PER_PLANE = 16;                                      // 3,520 f4/block
static constexpr int EXT_BLOCKS = NPLANES * EXTB_PER_PLANE;                    // 4416
static constexpr int INT_ROWS = NPLANES * HM_;                                 // 44,160 crop rows
static constexpr int ROWS_PER_WAVE = 8;                                        // 8 | 160 -> wave-uniform plane
static constexpr int INT_BLOCKS = INT_ROWS / (4 * ROWS_PER_WAVE);              // 1380
static constexpr int TOTAL_BLOCKS = INT_BLOCKS + SP_BLOCKS + EXT_BLOCKS;       // 7268

// ---------------------------------------------------------------------------
// One fused kernel, three roles (write-once canvas, all stores 16B-aligned,
// all global loads fully packed):
//  [0, INT_BLOCKS)   crop-band rows. Each wave owns 8 rows of ONE plane
//                    (wave-uniform plane/x0/y0/q/r, hoisted). All 8 row
//                    loads issued back-to-back (MLP=8), then rotate via
//                    shfl_up by uniform r, aligned stores + zero complement.
//  [+, SP_BLOCKS)    softplus + 4-way reduction -> partials
//  [+, EXT_BLOCKS)   exterior rows: two contiguous spans of pure zero stores
// ---------------------------------------------------------------------------
__global__ void fused_all(const float4* __restrict__ vol4,
                          float4* __restrict__ out_hf4,
                          float* __restrict__ partials,
                          const float4* __restrict__ hm4,
                          const int* __restrict__ centerHM,
                          float4* __restrict__ out_pad4) {
    const int gid = blockIdx.x;

    if (gid < INT_BLOCKS) {
        const int wgl  = gid * 4 + (threadIdx.x >> 6);   // wave id, 5520 total
        const int lane = threadIdx.x & 63;
        const float4 z = make_float4(0.f, 0.f, 0.f, 0.f);

        const int row0  = wgl * ROWS_PER_WAVE;           // 8 rows, same plane
        const int plane = row0 / HM_;                    // wave-uniform
        const int dy0   = row0 - plane * HM_;
        const int bcam  = plane / J_;

        const int cx = centerHM[bcam * 2 + 0];
        const int cy = centerHM[bcam * 2 + 1];
        const int x0 = min(max(cx / 2 - HM_ / 2, 0), W_ - HM_);
        const int y0 = min(max(cy / 2 - HM_ / 2, 0), H_ - HM_);
        const int q  = x0 >> 2;
        const int r  = x0 & 3;
        const int nspan = r ? (HM4 + 1) : HM4;           // 41 or 40
        const int cnt   = W4 - nspan;                    // 119 or 120

        const float4* __restrict__ src4 =
            hm4 + (long long)plane * (HM_ * HM4) + dy0 * HM4;
        float4* __restrict__ outp =
            out_pad4 + (long long)plane * PLANE_F4 + (y0 + dy0) * W4;

        // issue all 8 row loads first (8 independent loads in flight)
        float4 s[ROWS_PER_WAVE];
        #pragma unroll
        for (int i = 0; i < ROWS_PER_WAVE; ++i) {
            s[i] = (lane < HM4) ? src4[i * HM4 + lane] : z;
        }

        #pragma unroll
        for (int i = 0; i < ROWS_PER_WAVE; ++i) {
            float px = __shfl_up(s[i].x, 1, 64);
            float py = __shfl_up(s[i].y, 1, 64);
            float pz = __shfl_up(s[i].z, 1, 64);
            float pw = __shfl_up(s[i].w, 1, 64);
            if (lane == 0) { px = py = pz = pw = 0.f; }
            float4 v;
            switch (r) {                                 // wave-uniform
                case 0:  v = s[i]; break;
                case 1:  v = make_float4(pw, s[i].x, s[i].y, s[i].z); break;
                case 2:  v = make_float4(pz, pw, s[i].x, s[i].y); break;
                default: v = make_float4(py, pz, pw, s[i].x); break;
            }
            float4* __restrict__ outrow = outp + i * W4;
            if (lane < nspan) outrow[q + lane] = v;      // aligned packed store
            // zero complement of this row (write-once)
            if (lane < cnt) outrow[lane < q ? lane : lane + nspan] = z;
            const int l2 = lane + 64;
            if (l2 < cnt) outrow[l2 < q ? l2 : l2 + nspan] = z;
        }
        return;
    }

    if (gid < INT_BLOCKS + SP_BLOCKS) {
        // ---- softplus + reduction (pair-wise exact index math) ----
        const int sg = gid - INT_BLOCKS;
        const int NE4 = (D_ * D_ * D_) / 4;              // 31,250
        const int bj = sg / CHUNKS;
        const int chunk = sg % CHUNKS;
        const long long base4 = (long long)bj * NE4;

        float s = 0.f, sx = 0.f, sy = 0.f, sz = 0.f;
        for (int i = chunk * blockDim.x + threadIdx.x; i < NE4; i += CHUNKS * blockDim.x) {
            const float4 v = vol4[base4 + i];
            float4 sp;
            sp.x = fmaxf(v.x, 0.f) + log1pf(__expf(-fabsf(v.x)));
            sp.y = fmaxf(v.y, 0.f) + log1pf(__expf(-fabsf(v.y)));
            sp.z = fmaxf(v.z, 0.f) + log1pf(__expf(-fabsf(v.z)));
            sp.w = fmaxf(v.w, 0.f) + log1pf(__expf(-fabsf(v.w)));
            out_hf4[base4 + i] = sp;
            // e0 = 4i is even -> z0 even <= 48, pair (z0, z0+1) never wraps.
            const int e0 = i * 4;
            const int t0 = e0 / D_;       const int z0 = e0 - t0 * D_;
            const int x0i = t0 / D_;      const int y0i = t0 - x0i * D_;
            const int e2 = e0 + 2;
            const int t2 = e2 / D_;       const int z2 = e2 - t2 * D_;
            const int x2i = t2 / D_;      const int y2i = t2 - x2i * D_;
            const float p01 = sp.x + sp.y;
            const float p23 = sp.z + sp.w;
            s  += p01 + p23;
            sx += p01 * (float)x0i + p23 * (float)x2i;
            sy += p01 * (float)y0i + p23 * (float)y2i;
            sz += sp.x * (float)z0 + sp.y * (float)(z0 + 1)
                + sp.z * (float)z2 + sp.w * (float)(z2 + 1);
        }

        #pragma unroll
        for (int off = 32; off > 0; off >>= 1) {
            s  += __shfl_down(s,  off, 64);
            sx += __shfl_down(sx, off, 64);
            sy += __shfl_down(sy, off, 64);
            sz += __shfl_down(sz, off, 64);
        }
        __shared__ float sm[4][4];
        const int lane = threadIdx.x & 63;
        const int wid  = threadIdx.x >> 6;
        if (lane == 0) {
            sm[0][wid] = s; sm[1][wid] = sx; sm[2][wid] = sy; sm[3][wid] = sz;
        }
        __syncthreads();
        if (threadIdx.x == 0) {
            float a0 = 0.f, a1 = 0.f, a2 = 0.f, a3 = 0.f;
            #pragma unroll
            for (int w = 0; w < 4; ++w) {
                a0 += sm[0][w]; a1 += sm[1][w]; a2 += sm[2][w]; a3 += sm[3][w];
            }
            partials[sg * 4 + 0] = a0;
            partials[sg * 4 + 1] = a1;
            partials[sg * 4 + 2] = a2;
            partials[sg * 4 + 3] = a3;
        }
        return;
    }

    // ---- exterior zero rows: two contiguous spans, pure stores ----
    {
        const int pb    = gid - INT_BLOCKS - SP_BLOCKS;
        const int plane = pb >> 4;                       // / EXTB_PER_PLANE
        const int sub   = pb & (EXTB_PER_PLANE - 1);
        const int bcam  = plane / J_;                    // uniform (scalar)

        const int cy = centerHM[bcam * 2 + 1];
        const int y0 = min(max(cy / 2 - HM_ / 2, 0), H_ - HM_);
        const int top = y0 * W4;                         // f4 before crop band

        float4* __restrict__ outp = out_pad4 + (long long)plane * PLANE_F4;
        const float4 z = make_float4(0.f, 0.f, 0.f, 0.f);
        const int e_end = (sub + 1) * (EXT_F4 / EXTB_PER_PLANE);
        for (int e = sub * (EXT_F4 / EXTB_PER_PLANE) + threadIdx.x; e < e_end; e += 256) {
            const int dst = e < top ? e : e + INT_F4;    // skip the crop band
            outp[dst] = z;
        }
    }
}

// ---------------------------------------------------------------------------
// Tiny finalize (1 block)
// ---------------------------------------------------------------------------
__global__ void finalize_points(const float* __restrict__ partials,
                                const float* __restrict__ c3d,
                                float* __restrict__ out_p3d) {
    const int bj = threadIdx.x;
    if (bj < NBJ) {
        const int b = bj / J_;
        float a0 = 0.f, a1 = 0.f, a2 = 0.f, a3 = 0.f;
        for (int c = 0; c < CHUNKS; ++c) {
            const float* p = &partials[(bj * CHUNKS + c) * 4];
            a0 += p[0]; a1 += p[1]; a2 += p[2]; a3 += p[3];
        }
        const float inv = 1.0f / a0;
        out_p3d[bj * 3 + 0] = a1 * inv * 4.0f - 100.0f + c3d[b * 3 + 0];
        out_p3d[bj * 3 + 1] = a2 * inv * 4.0f - 100.0f + c3d[b * 3 + 1];
        out_p3d[bj * 3 + 2] = a3 * inv * 4.0f - 100.0f + c3d[b * 3 + 2];
    }
}

extern "C" void kernel_launch(void* const* d_in, const int* in_sizes, int n_in,
                              void* d_out, int out_size, void* d_ws, size_t ws_size,
                              hipStream_t stream) {
    const float* hm_batch  = (const float*)d_in[0];   // [B,NCAM,J,HM,HM]
    const float* vol       = (const float*)d_in[1];   // [B,J,D,D,D]
    const float* c3d       = (const float*)d_in[2];   // [B,1,3]
    const int*   centerHM  = (const int*)d_in[3];     // [B,NCAM,2]

    float* out     = (float*)d_out;
    float* out_hf  = out;                              // heatmap_final
    float* out_pad = out + HF_SIZE;                    // heatmaps_padded (16B-aligned)
    float* out_p3d = out + HF_SIZE + HP_SIZE;          // points3D

    float* partials = (float*)d_ws;                    // [SP_BLOCKS*4]

    fused_all<<<TOTAL_BLOCKS, 256, 0, stream>>>(
        (const float4*)vol, (float4*)out_hf, partials,
        (const float4*)hm_batch, centerHM, (float4*)out_pad);

    finalize_points<<<1, 64, 0, stream>>>(partials, c3d, out_p3d);
}